// Round 19
// baseline (99.395 us; speedup 1.0000x reference)
//
#include <hip/hip_runtime.h>
#include <math.h>

// Problem constants
constexpr int N = 8, C = 128, H = 64, W = 64;
constexpr int PIX = H * W;            // 4096
constexpr int KK = 49;                // 7x7 window

// ws layout (floats) — first 32768 floats hold 4 bf16 A-matrices (hi/lo x 2)
constexpr size_t Z_OFF   = 65536;                    // z = M^T x
constexpr size_t YSZ     = (size_t)N * C * PIX;      // 4,194,304
constexpr size_t SIM_OFF = Z_OFF + YSZ;              // sim fp32 [g=128][49][256]
constexpr size_t SIMSZ   = (size_t)N * 16 * KK * 256;// 1,605,632
constexpr size_t U_OFF   = SIM_OFF + SIMSZ;          // u = PV(x)

constexpr int SLW = 76;   // fp32 stage row width (simk6, softpv10)
constexpr int ALW = 136;  // convm LDS row stride (ushorts)

typedef __attribute__((ext_vector_type(8))) short bf16x8;
typedef __attribute__((ext_vector_type(4))) float f32x4;

__device__ __forceinline__ unsigned bf16rne(float f) {
    unsigned u = __float_as_uint(f);
    u += 0x7FFFu + ((u >> 16) & 1u);
    return u >> 16;
}
__device__ __forceinline__ unsigned packbf(float a, float b) {
    return bf16rne(a) | (bf16rne(b) << 16);
}
__device__ __forceinline__ float bflo(unsigned u) { return __uint_as_float(u << 16); }
__device__ __forceinline__ float bfhi(unsigned u) { return __uint_as_float(u & 0xFFFF0000u); }

// ---------------------------------------------------------------------------
// K0: prep — M = W1^T W2 -> A1 hi/lo bf16; W3 -> A2 hi/lo bf16.  (r15)
// ---------------------------------------------------------------------------
__global__ __launch_bounds__(256) void prep(const float* __restrict__ w1,
                                            const float* __restrict__ w2,
                                            const float* __restrict__ w3,
                                            unsigned short* __restrict__ A1hi,
                                            unsigned short* __restrict__ A1lo,
                                            unsigned short* __restrict__ A2hi,
                                            unsigned short* __restrict__ A2lo) {
    int bid = blockIdx.x, tid = threadIdx.x;
    if (bid < 64) {
        int a = bid * 2 + (tid >> 7);
        int b = tid & 127;
        float s = 0.f;
        for (int c = 0; c < 128; c++)
            s = fmaf(w1[c * 128 + a], w2[c * 128 + b], s);
        unsigned h = bf16rne(s);
        float lo = s - __uint_as_float(h << 16);
        A1hi[b * 128 + a] = (unsigned short)h;
        A1lo[b * 128 + a] = (unsigned short)bf16rne(lo);
    } else {
        int base = (bid - 64) * 4096;
        for (int i = tid; i < 4096; i += 256) {
            int idx = base + i;
            float v = w3[idx];
            unsigned h = bf16rne(v);
            float lo = v - __uint_as_float(h << 16);
            A2hi[idx] = (unsigned short)h;
            A2lo[idx] = (unsigned short)bf16rne(lo);
        }
    }
}

// ---------------------------------------------------------------------------
// K1: split-precision MFMA 1x1-conv (r15, measured-good, unchanged).
// ---------------------------------------------------------------------------
__global__ __launch_bounds__(256) void convm(const unsigned short* __restrict__ Ahi,
                                             const unsigned short* __restrict__ Alo,
                                             const float* __restrict__ Bsrc,
                                             float* __restrict__ Yout) {
    __shared__ __align__(16) unsigned short xh[64 * ALW];
    __shared__ __align__(16) unsigned short xl[64 * ALW];

    int bid = blockIdx.x;
    int pt  = bid & 63;
    int n   = bid >> 6;
    int p0  = pt * 64;

    const float* B = Bsrc + (size_t)n * C * PIX;
    float*       Y = Yout + (size_t)n * C * PIX;

    int tid  = threadIdx.x;
    int wid  = tid >> 6;
    int lane = tid & 63;
    int l15  = lane & 15;
    int lg   = lane >> 4;

    unsigned* xhd = (unsigned*)xh;
    unsigned* xld = (unsigned*)xl;
#pragma unroll
    for (int i = 0; i < 4; i++) {
        int q  = tid + i * 256;
        int cp = q >> 4;
        int f  = q & 15;
        float4 va = *(const float4*)&B[(size_t)(2 * cp) * PIX + p0 + f * 4];
        float4 vb = *(const float4*)&B[(size_t)(2 * cp + 1) * PIX + p0 + f * 4];
        const float* pa = (const float*)&va;
        const float* pb = (const float*)&vb;
#pragma unroll
        for (int j = 0; j < 4; j++) {
            unsigned ha = bf16rne(pa[j]);
            unsigned hb = bf16rne(pb[j]);
            float la = pa[j] - __uint_as_float(ha << 16);
            float lb = pb[j] - __uint_as_float(hb << 16);
            xhd[(f * 4 + j) * 68 + cp] = ha | (hb << 16);
            xld[(f * 4 + j) * 68 + cp] = bf16rne(la) | (bf16rne(lb) << 16);
        }
    }
    __syncthreads();

    f32x4 acc[2][4];
#pragma unroll
    for (int t = 0; t < 2; t++)
#pragma unroll
        for (int p = 0; p < 4; p++) acc[t][p] = (f32x4){0.f, 0.f, 0.f, 0.f};

#pragma unroll
    for (int kc = 0; kc < 4; kc++) {
        int k0 = kc * 32 + lg * 8;
        bf16x8 ah[2], al_[2], bh[4], bl[4];
#pragma unroll
        for (int t = 0; t < 2; t++) {
            int row = wid * 32 + t * 16 + l15;
            ah[t]  = *(const bf16x8*)&Ahi[row * 128 + k0];
            al_[t] = *(const bf16x8*)&Alo[row * 128 + k0];
        }
#pragma unroll
        for (int p = 0; p < 4; p++) {
            bh[p] = *(const bf16x8*)&xh[(p * 16 + l15) * ALW + k0];
            bl[p] = *(const bf16x8*)&xl[(p * 16 + l15) * ALW + k0];
        }
#pragma unroll
        for (int t = 0; t < 2; t++)
#pragma unroll
            for (int p = 0; p < 4; p++) {
                acc[t][p] = __builtin_amdgcn_mfma_f32_16x16x32_bf16(
                    ah[t], bh[p], acc[t][p], 0, 0, 0);
                acc[t][p] = __builtin_amdgcn_mfma_f32_16x16x32_bf16(
                    ah[t], bl[p], acc[t][p], 0, 0, 0);
                acc[t][p] = __builtin_amdgcn_mfma_f32_16x16x32_bf16(
                    al_[t], bh[p], acc[t][p], 0, 0, 0);
            }
    }

#pragma unroll
    for (int t = 0; t < 2; t++) {
#pragma unroll
        for (int p = 0; p < 4; p++) {
#pragma unroll
            for (int reg = 0; reg < 4; reg++) {
                int oc = wid * 32 + t * 16 + lg * 4 + reg;
                int px = p0 + p * 16 + l15;
                Y[(size_t)oc * PIX + px] = acc[t][p][reg];
            }
        }
    }
}

// ---------------------------------------------------------------------------
// K2: simk6 — async-stage split + z prefetch (r16/r17, measured best).
// (simk7 double-buffer REVERTED: LDS-BW bound, not barrier-bound.)
// ---------------------------------------------------------------------------
__global__ __launch_bounds__(256) void simk6(const float* __restrict__ z,
                                             const float* __restrict__ x,
                                             float* __restrict__ sim) {
    __shared__ __align__(16) float st[5376];

    int bid = blockIdx.x;
    int di  = bid >> 7;
    int g   = bid & 127;
    int n   = g >> 4;
    int hq  = g & 15;
    int h0  = hq * 4;

    int tid  = threadIdx.x;
    int wid  = tid >> 6;
    int lane = tid & 63;
    int r = lane >> 4, w4 = lane & 15, wpx = w4 * 4;
    int qw = tid & 15, qc = (tid >> 4) & 15;

    const float* zb = z + (size_t)n * C * PIX;
    const float* xb = x + (size_t)n * C * PIX;
    float* simb = sim + ((size_t)g * KK) * 256;

    for (int idx = tid; idx < 16 * 4 * 8; idx += 256) {
        int col8 = idx & 7;
        int row  = (idx >> 3) & 3;
        int c    = idx >> 5;
        int col  = (col8 < 4) ? col8 : 64 + col8;
        st[(c * 4 + row) * SLW + col] = 0.f;
    }

    float acc[7][4];
#pragma unroll
    for (int dj = 0; dj < 7; dj++)
#pragma unroll
        for (int j = 0; j < 4; j++) acc[dj][j] = 0.f;

    int hh0 = h0 + di - 3;
    float4 xs[2][4], zs[2][4];

#pragma unroll
    for (int i = 0; i < 4; i++) {
        int hh = hh0 + i;
        float4 v = make_float4(0.f, 0.f, 0.f, 0.f);
        if ((unsigned)hh < 64u)
            v = *(const float4*)&xb[(size_t)qc * PIX + hh * 64 + qw * 4];
        xs[0][i] = v;
    }
#pragma unroll
    for (int c = 0; c < 4; c++)
        zs[0][c] = *(const float4*)&zb[(size_t)(wid * 4 + c) * PIX + (h0 + r) * 64 + wpx];

#pragma unroll
    for (int ch = 0; ch < 8; ch++) {
        int cur = ch & 1, nxt = cur ^ 1;
#pragma unroll
        for (int i = 0; i < 4; i++)
            *(float4*)&st[(qc * 4 + i) * SLW + 4 + qw * 4] = xs[cur][i];
        if (ch < 7) {
            int cb = (ch + 1) * 16;
#pragma unroll
            for (int i = 0; i < 4; i++) {
                int hh = hh0 + i;
                float4 v = make_float4(0.f, 0.f, 0.f, 0.f);
                if ((unsigned)hh < 64u)
                    v = *(const float4*)&xb[(size_t)(cb + qc) * PIX + hh * 64 + qw * 4];
                xs[nxt][i] = v;
            }
#pragma unroll
            for (int c = 0; c < 4; c++)
                zs[nxt][c] = *(const float4*)&zb[(size_t)(cb + wid * 4 + c) * PIX
                                                 + (h0 + r) * 64 + wpx];
        }
        __syncthreads();

#pragma unroll
        for (int c = 0; c < 4; c++) {
            int cl = wid * 4 + c;
            const float* rp = &st[(cl * 4 + r) * SLW + wpx];
            float rw[12];
            *(float4*)&rw[0] = *(const float4*)&rp[0];
            *(float4*)&rw[4] = *(const float4*)&rp[4];
            *(float4*)&rw[8] = *(const float4*)&rp[8];
            const float* zp = (const float*)&zs[cur][c];
#pragma unroll
            for (int dj = 0; dj < 7; dj++)
#pragma unroll
                for (int j = 0; j < 4; j++)
                    acc[dj][j] = fmaf(zp[j], rw[j + dj + 1], acc[dj][j]);
        }
        __syncthreads();
    }

    if (wid > 0) {
#pragma unroll
        for (int dj = 0; dj < 7; dj++) {
            float4 v = make_float4(acc[dj][0], acc[dj][1], acc[dj][2], acc[dj][3]);
            *(float4*)&st[((wid - 1) * 7 + dj) * 256 + lane * 4] = v;
        }
    }
    __syncthreads();
    if (wid == 0) {
#pragma unroll
        for (int s = 0; s < 3; s++)
#pragma unroll
            for (int dj = 0; dj < 7; dj++) {
                float4 v = *(const float4*)&st[(s * 7 + dj) * 256 + lane * 4];
                acc[dj][0] += v.x; acc[dj][1] += v.y;
                acc[dj][2] += v.z; acc[dj][3] += v.w;
            }
#pragma unroll
        for (int dj = 0; dj < 7; dj++) {
            int k = di * 7 + dj;
            float4 v = make_float4(acc[dj][0], acc[dj][1], acc[dj][2], acc[dj][3]);
            *(float4*)&simb[(size_t)k * 256 + r * 64 + wpx] = v;
        }
    }
}

// ---------------------------------------------------------------------------
// K3: softpv10 — softpv9 with FP32 window stage (no pack/unpack on the
// window path: ~336 VALU ops/lane saved).  attn stays bf16 (LDS fit).
// LDS 48.6 + 25.1 + 1 = 74.8 KB -> 2 blocks/CU (same as before: VGPR-capped).
// T14 prefetch + deferred normalization unchanged.
// ---------------------------------------------------------------------------
__global__ __launch_bounds__(512) void softpv10(const float* __restrict__ sim,
                                                const float* __restrict__ x,
                                                float* __restrict__ u) {
    __shared__ __align__(16) float stf[16 * 10 * SLW];      // 48,640 B fp32
    __shared__ __align__(16) unsigned short al[KK * 256];   // 25,088 B bf16
    __shared__ float sinv[256];                             // 1,024 B
    float* mred = stf;          // [2][256] alias (stage dead during softmax)
    float* sred = stf + 512;    // [2][256]

    int bid = blockIdx.x;
    int cqb = bid >> 7;
    int g   = bid & 127;
    int n   = g >> 4;
    int hq  = g & 15;
    int h0  = hq * 4;

    int tid  = threadIdx.x;
    int wid  = tid >> 6;
    int lane = tid & 63;
    int r = lane >> 4, w4 = lane & 15, wpx = w4 * 4;

    const float* simb = sim + (size_t)g * KK * 256;
    const float* xb   = x + (size_t)n * C * PIX;
    float* ub = u + (size_t)n * C * PIX;

    // staging-role indices (fixed per thread, 5 tiles each)
    int sqw[5], sqc[5], sqr[5];
#pragma unroll
    for (int i = 0; i < 5; i++) {
        int q  = tid + i * 512;
        sqw[i] = q & 15; sqc[i] = (q >> 4) & 15; sqr[i] = q >> 8;
    }

    float4 xs[5];
    // ---- T14: issue chunk-0 loads NOW; latency hides under softmax ----
    {
        int c0 = cqb * 32;
#pragma unroll
        for (int i = 0; i < 5; i++) {
            int hh = h0 - 3 + sqr[i];
            float4 v = make_float4(0.f, 0.f, 0.f, 0.f);
            if ((unsigned)hh < 64u)
                v = *(const float4*)&xb[(size_t)(c0 + sqc[i]) * PIX + hh * 64 + sqw[i] * 4];
            xs[i] = v;
        }
    }

    // ---- softmax (deferred normalization) ----
    {
        int ks = tid >> 8;
        int px = tid & 255;
        int k0 = ks ? 25 : 0;
        int nk = ks ? 24 : 25;
        float m = -1e30f;
        for (int i = 0; i < nk; i++)
            m = fmaxf(m, simb[(size_t)(k0 + i) * 256 + px]);
        mred[ks * 256 + px] = m;
        __syncthreads();
        m = fmaxf(mred[px], mred[256 + px]);
        float s = 0.f;
        for (int i = 0; i < nk; i++) {
            float e = __expf(simb[(size_t)(k0 + i) * 256 + px] - m);
            s += e;
            al[(k0 + i) * 256 + px] = (unsigned short)bf16rne(e);
        }
        sred[ks * 256 + px] = s;
        __syncthreads();
        if (ks == 0) sinv[px] = 1.f / (sred[px] + sred[256 + px]);
    }
    __syncthreads();   // sred reads done; stf reusable

    // ---- halo zero (fp32) ----
    for (int idx = tid; idx < 16 * 10 * 12; idx += 512) {
        int i12  = idx % 12;
        int rowc = idx / 12;
        int col  = (i12 < 4) ? i12 : 64 + i12;
        stf[rowc * SLW + col] = 0.f;
    }

    // ---- chunk 0: write prefetched regs to LDS (fp32); issue chunk-1 loads ----
#pragma unroll
    for (int i = 0; i < 5; i++)
        *(float4*)&stf[(sqc[i] * 10 + sqr[i]) * SLW + 4 + sqw[i] * 4] = xs[i];
    {
        int c1 = cqb * 32 + 16;
#pragma unroll
        for (int i = 0; i < 5; i++) {
            int hh = h0 - 3 + sqr[i];
            float4 v = make_float4(0.f, 0.f, 0.f, 0.f);
            if ((unsigned)hh < 64u)
                v = *(const float4*)&xb[(size_t)(c1 + sqc[i]) * PIX + hh * 64 + sqw[i] * 4];
            xs[i] = v;
        }
    }
    __syncthreads();   // chunk-0 stage visible

    int cw = wid * 2;
#pragma unroll
    for (int ch2 = 0; ch2 < 2; ch2++) {
        int c0 = cqb * 32 + ch2 * 16;
        float u4[2][4];
#pragma unroll
        for (int cl = 0; cl < 2; cl++)
#pragma unroll
            for (int j = 0; j < 4; j++) u4[cl][j] = 0.f;

        for (int di = 0; di < 7; di++) {
#pragma unroll
            for (int cl = 0; cl < 2; cl++) {
                const float* rp = &stf[((cw + cl) * 10 + r + di) * SLW + wpx];
                float rw[12];
                *(float4*)&rw[0] = *(const float4*)&rp[0];
                *(float4*)&rw[4] = *(const float4*)&rp[4];
                *(float4*)&rw[8] = *(const float4*)&rp[8];
#pragma unroll
                for (int dj = 0; dj < 7; dj++) {
                    uint2 p = *(const uint2*)&al[(di * 7 + dj) * 256 + r * 64 + wpx];
                    float a0 = bflo(p.x), a1 = bfhi(p.x);
                    float a2 = bflo(p.y), a3 = bfhi(p.y);
                    u4[cl][0] = fmaf(a0, rw[dj + 1], u4[cl][0]);
                    u4[cl][1] = fmaf(a1, rw[dj + 2], u4[cl][1]);
                    u4[cl][2] = fmaf(a2, rw[dj + 3], u4[cl][2]);
                    u4[cl][3] = fmaf(a3, rw[dj + 4], u4[cl][3]);
                }
            }
        }

        float4 s4 = *(const float4*)&sinv[r * 64 + wpx];
        const float* sp = (const float*)&s4;
#pragma unroll
        for (int cl = 0; cl < 2; cl++) {
            int c = c0 + cw + cl;
            float4 v = make_float4(u4[cl][0] * sp[0], u4[cl][1] * sp[1],
                                   u4[cl][2] * sp[2], u4[cl][3] * sp[3]);
            *(float4*)&ub[(size_t)c * PIX + (h0 + r) * 64 + wpx] = v;
        }

        if (ch2 == 0) {
            __syncthreads();   // chunk-0 compute done; stf writable
#pragma unroll
            for (int i = 0; i < 5; i++)
                *(float4*)&stf[(sqc[i] * 10 + sqr[i]) * SLW + 4 + sqw[i] * 4] = xs[i];
            __syncthreads();   // chunk-1 stage visible
        }
    }
}

// ---------------------------------------------------------------------------
extern "C" void kernel_launch(void* const* d_in, const int* in_sizes, int n_in,
                              void* d_out, int out_size, void* d_ws, size_t ws_size,
                              hipStream_t stream) {
    const float* x  = (const float*)d_in[0];
    const float* w1 = (const float*)d_in[1];
    const float* w2 = (const float*)d_in[2];
    const float* w3 = (const float*)d_in[3];
    float* wsf = (float*)d_ws;
    unsigned short* A1hi = (unsigned short*)wsf;
    unsigned short* A1lo = A1hi + 16384;
    unsigned short* A2hi = A1hi + 32768;
    unsigned short* A2lo = A1hi + 49152;

    prep<<<68, 256, 0, stream>>>(w1, w2, w3, A1hi, A1lo, A2hi, A2lo);
    convm<<<512, 256, 0, stream>>>(A1hi, A1lo, x, wsf + Z_OFF);             // z
    simk6<<<896, 256, 0, stream>>>(wsf + Z_OFF, x, wsf + SIM_OFF);          // sim
    softpv10<<<512, 512, 0, stream>>>(wsf + SIM_OFF, x, wsf + U_OFF);       // softmax+PV
    convm<<<512, 256, 0, stream>>>(A2hi, A2lo, wsf + U_OFF, (float*)d_out); // out
}

// Round 20
// 90.318 us; speedup vs baseline: 1.1005x; 1.1005x over previous
//
#include <hip/hip_runtime.h>
#include <math.h>

// Problem constants
constexpr int N = 8, C = 128, H = 64, W = 64;
constexpr int PIX = H * W;            // 4096
constexpr int KK = 49;                // 7x7 window

// ws layout (floats) — first 32768 floats hold 4 bf16 A-matrices (hi/lo x 2)
constexpr size_t Z_OFF   = 65536;                    // z = M^T x
constexpr size_t YSZ     = (size_t)N * C * PIX;      // 4,194,304
constexpr size_t SIM_OFF = Z_OFF + YSZ;              // simp fp32 x2 [g][49][256]
constexpr size_t SIMSZ   = (size_t)N * 16 * KK * 256;// 1,605,632
constexpr size_t U_OFF   = SIM_OFF + 2 * SIMSZ;      // u = PV(x)

constexpr int SLW = 76;   // fp32 stage row width (simk8)
constexpr int SBW = 76;   // bf16 stage row width in ushorts (softpv9)
constexpr int ALW = 136;  // convm LDS row stride (ushorts)

typedef __attribute__((ext_vector_type(8))) short bf16x8;
typedef __attribute__((ext_vector_type(4))) float f32x4;

__device__ __forceinline__ unsigned bf16rne(float f) {
    unsigned u = __float_as_uint(f);
    u += 0x7FFFu + ((u >> 16) & 1u);
    return u >> 16;
}
__device__ __forceinline__ unsigned packbf(float a, float b) {
    return bf16rne(a) | (bf16rne(b) << 16);
}
__device__ __forceinline__ float bflo(unsigned u) { return __uint_as_float(u << 16); }
__device__ __forceinline__ float bfhi(unsigned u) { return __uint_as_float(u & 0xFFFF0000u); }

// ---------------------------------------------------------------------------
// K0: prep — M = W1^T W2 -> A1 hi/lo bf16; W3 -> A2 hi/lo bf16.  (r15)
// ---------------------------------------------------------------------------
__global__ __launch_bounds__(256) void prep(const float* __restrict__ w1,
                                            const float* __restrict__ w2,
                                            const float* __restrict__ w3,
                                            unsigned short* __restrict__ A1hi,
                                            unsigned short* __restrict__ A1lo,
                                            unsigned short* __restrict__ A2hi,
                                            unsigned short* __restrict__ A2lo) {
    int bid = blockIdx.x, tid = threadIdx.x;
    if (bid < 64) {
        int a = bid * 2 + (tid >> 7);
        int b = tid & 127;
        float s = 0.f;
        for (int c = 0; c < 128; c++)
            s = fmaf(w1[c * 128 + a], w2[c * 128 + b], s);
        unsigned h = bf16rne(s);
        float lo = s - __uint_as_float(h << 16);
        A1hi[b * 128 + a] = (unsigned short)h;
        A1lo[b * 128 + a] = (unsigned short)bf16rne(lo);
    } else {
        int base = (bid - 64) * 4096;
        for (int i = tid; i < 4096; i += 256) {
            int idx = base + i;
            float v = w3[idx];
            unsigned h = bf16rne(v);
            float lo = v - __uint_as_float(h << 16);
            A2hi[idx] = (unsigned short)h;
            A2lo[idx] = (unsigned short)bf16rne(lo);
        }
    }
}

// ---------------------------------------------------------------------------
// K1: split-precision MFMA 1x1-conv (r15, measured-good, unchanged).
// ---------------------------------------------------------------------------
__global__ __launch_bounds__(256) void convm(const unsigned short* __restrict__ Ahi,
                                             const unsigned short* __restrict__ Alo,
                                             const float* __restrict__ Bsrc,
                                             float* __restrict__ Yout) {
    __shared__ __align__(16) unsigned short xh[64 * ALW];
    __shared__ __align__(16) unsigned short xl[64 * ALW];

    int bid = blockIdx.x;
    int pt  = bid & 63;
    int n   = bid >> 6;
    int p0  = pt * 64;

    const float* B = Bsrc + (size_t)n * C * PIX;
    float*       Y = Yout + (size_t)n * C * PIX;

    int tid  = threadIdx.x;
    int wid  = tid >> 6;
    int lane = tid & 63;
    int l15  = lane & 15;
    int lg   = lane >> 4;

    unsigned* xhd = (unsigned*)xh;
    unsigned* xld = (unsigned*)xl;
#pragma unroll
    for (int i = 0; i < 4; i++) {
        int q  = tid + i * 256;
        int cp = q >> 4;
        int f  = q & 15;
        float4 va = *(const float4*)&B[(size_t)(2 * cp) * PIX + p0 + f * 4];
        float4 vb = *(const float4*)&B[(size_t)(2 * cp + 1) * PIX + p0 + f * 4];
        const float* pa = (const float*)&va;
        const float* pb = (const float*)&vb;
#pragma unroll
        for (int j = 0; j < 4; j++) {
            unsigned ha = bf16rne(pa[j]);
            unsigned hb = bf16rne(pb[j]);
            float la = pa[j] - __uint_as_float(ha << 16);
            float lb = pb[j] - __uint_as_float(hb << 16);
            xhd[(f * 4 + j) * 68 + cp] = ha | (hb << 16);
            xld[(f * 4 + j) * 68 + cp] = bf16rne(la) | (bf16rne(lb) << 16);
        }
    }
    __syncthreads();

    f32x4 acc[2][4];
#pragma unroll
    for (int t = 0; t < 2; t++)
#pragma unroll
        for (int p = 0; p < 4; p++) acc[t][p] = (f32x4){0.f, 0.f, 0.f, 0.f};

#pragma unroll
    for (int kc = 0; kc < 4; kc++) {
        int k0 = kc * 32 + lg * 8;
        bf16x8 ah[2], al_[2], bh[4], bl[4];
#pragma unroll
        for (int t = 0; t < 2; t++) {
            int row = wid * 32 + t * 16 + l15;
            ah[t]  = *(const bf16x8*)&Ahi[row * 128 + k0];
            al_[t] = *(const bf16x8*)&Alo[row * 128 + k0];
        }
#pragma unroll
        for (int p = 0; p < 4; p++) {
            bh[p] = *(const bf16x8*)&xh[(p * 16 + l15) * ALW + k0];
            bl[p] = *(const bf16x8*)&xl[(p * 16 + l15) * ALW + k0];
        }
#pragma unroll
        for (int t = 0; t < 2; t++)
#pragma unroll
            for (int p = 0; p < 4; p++) {
                acc[t][p] = __builtin_amdgcn_mfma_f32_16x16x32_bf16(
                    ah[t], bh[p], acc[t][p], 0, 0, 0);
                acc[t][p] = __builtin_amdgcn_mfma_f32_16x16x32_bf16(
                    ah[t], bl[p], acc[t][p], 0, 0, 0);
                acc[t][p] = __builtin_amdgcn_mfma_f32_16x16x32_bf16(
                    al_[t], bh[p], acc[t][p], 0, 0, 0);
            }
    }

#pragma unroll
    for (int t = 0; t < 2; t++) {
#pragma unroll
        for (int p = 0; p < 4; p++) {
#pragma unroll
            for (int reg = 0; reg < 4; reg++) {
                int oc = wid * 32 + t * 16 + lg * 4 + reg;
                int px = p0 + p * 16 + l15;
                Y[(size_t)oc * PIX + px] = acc[t][p][reg];
            }
        }
    }
}

// ---------------------------------------------------------------------------
// K2: simk8 — simk6 structure with CHANNEL-HALF SPLIT: grid 1792 =
// (chalf(2) x di(7)) x g(128).  Each block: 4 chunks over its 64 channels,
// writes simp[chalf][g][k][px].  2x wave parallelism (7 waves/SIMD), half
// the per-block serial chain.  T14 prefetch ping-pong kept.
// ---------------------------------------------------------------------------
__global__ __launch_bounds__(256) void simk8(const float* __restrict__ z,
                                             const float* __restrict__ x,
                                             float* __restrict__ simp) {
    __shared__ __align__(16) float st[5376];

    int bid = blockIdx.x;
    int t7  = bid >> 7;          // 0..13
    int di  = t7 % 7;
    int chalf = t7 / 7;
    int g   = bid & 127;
    int n   = g >> 4;
    int hq  = g & 15;
    int h0  = hq * 4;
    int cbase = chalf * 64;

    int tid  = threadIdx.x;
    int wid  = tid >> 6;
    int lane = tid & 63;
    int r = lane >> 4, w4 = lane & 15, wpx = w4 * 4;
    int qw = tid & 15, qc = (tid >> 4) & 15;

    const float* zb = z + (size_t)n * C * PIX;
    const float* xb = x + (size_t)n * C * PIX;
    float* simb = simp + (size_t)chalf * SIMSZ + ((size_t)g * KK) * 256;

    for (int idx = tid; idx < 16 * 4 * 8; idx += 256) {
        int col8 = idx & 7;
        int row  = (idx >> 3) & 3;
        int c    = idx >> 5;
        int col  = (col8 < 4) ? col8 : 64 + col8;
        st[(c * 4 + row) * SLW + col] = 0.f;
    }

    float acc[7][4];
#pragma unroll
    for (int dj = 0; dj < 7; dj++)
#pragma unroll
        for (int j = 0; j < 4; j++) acc[dj][j] = 0.f;

    int hh0 = h0 + di - 3;
    float4 xs[2][4], zs[2][4];

#pragma unroll
    for (int i = 0; i < 4; i++) {
        int hh = hh0 + i;
        float4 v = make_float4(0.f, 0.f, 0.f, 0.f);
        if ((unsigned)hh < 64u)
            v = *(const float4*)&xb[(size_t)(cbase + qc) * PIX + hh * 64 + qw * 4];
        xs[0][i] = v;
    }
#pragma unroll
    for (int c = 0; c < 4; c++)
        zs[0][c] = *(const float4*)&zb[(size_t)(cbase + wid * 4 + c) * PIX
                                       + (h0 + r) * 64 + wpx];

#pragma unroll
    for (int ch = 0; ch < 4; ch++) {
        int cur = ch & 1, nxt = cur ^ 1;
#pragma unroll
        for (int i = 0; i < 4; i++)
            *(float4*)&st[(qc * 4 + i) * SLW + 4 + qw * 4] = xs[cur][i];
        if (ch < 3) {
            int cb = cbase + (ch + 1) * 16;
#pragma unroll
            for (int i = 0; i < 4; i++) {
                int hh = hh0 + i;
                float4 v = make_float4(0.f, 0.f, 0.f, 0.f);
                if ((unsigned)hh < 64u)
                    v = *(const float4*)&xb[(size_t)(cb + qc) * PIX + hh * 64 + qw * 4];
                xs[nxt][i] = v;
            }
#pragma unroll
            for (int c = 0; c < 4; c++)
                zs[nxt][c] = *(const float4*)&zb[(size_t)(cb + wid * 4 + c) * PIX
                                                 + (h0 + r) * 64 + wpx];
        }
        __syncthreads();

#pragma unroll
        for (int c = 0; c < 4; c++) {
            int cl = wid * 4 + c;
            const float* rp = &st[(cl * 4 + r) * SLW + wpx];
            float rw[12];
            *(float4*)&rw[0] = *(const float4*)&rp[0];
            *(float4*)&rw[4] = *(const float4*)&rp[4];
            *(float4*)&rw[8] = *(const float4*)&rp[8];
            const float* zp = (const float*)&zs[cur][c];
#pragma unroll
            for (int dj = 0; dj < 7; dj++)
#pragma unroll
                for (int j = 0; j < 4; j++)
                    acc[dj][j] = fmaf(zp[j], rw[j + dj + 1], acc[dj][j]);
        }
        __syncthreads();
    }

    if (wid > 0) {
#pragma unroll
        for (int dj = 0; dj < 7; dj++) {
            float4 v = make_float4(acc[dj][0], acc[dj][1], acc[dj][2], acc[dj][3]);
            *(float4*)&st[((wid - 1) * 7 + dj) * 256 + lane * 4] = v;
        }
    }
    __syncthreads();
    if (wid == 0) {
#pragma unroll
        for (int s = 0; s < 3; s++)
#pragma unroll
            for (int dj = 0; dj < 7; dj++) {
                float4 v = *(const float4*)&st[(s * 7 + dj) * 256 + lane * 4];
                acc[dj][0] += v.x; acc[dj][1] += v.y;
                acc[dj][2] += v.z; acc[dj][3] += v.w;
            }
#pragma unroll
        for (int dj = 0; dj < 7; dj++) {
            int k = di * 7 + dj;
            float4 v = make_float4(acc[dj][0], acc[dj][1], acc[dj][2], acc[dj][3]);
            *(float4*)&simb[(size_t)k * 256 + r * 64 + wpx] = v;
        }
    }
}

// ---------------------------------------------------------------------------
// K3: softpv9 (r17, measured best) + partial-sim FOLD in softmax
// (sv = simb[..] + simb2[..]; both L2-resident, loads hide under T14 prefetch)
// ---------------------------------------------------------------------------
__global__ __launch_bounds__(512) void softpv9(const float* __restrict__ simp,
                                               const float* __restrict__ x,
                                               float* __restrict__ u) {
    __shared__ __align__(16) unsigned short stb[16 * 10 * SBW];
    __shared__ __align__(16) unsigned short al[KK * 256];
    __shared__ float sinv[256];
    float* mred = (float*)stb;
    float* sred = (float*)stb + 512;

    int bid = blockIdx.x;
    int cqb = bid >> 7;
    int g   = bid & 127;
    int n   = g >> 4;
    int hq  = g & 15;
    int h0  = hq * 4;

    int tid  = threadIdx.x;
    int wid  = tid >> 6;
    int lane = tid & 63;
    int r = lane >> 4, w4 = lane & 15, wpx = w4 * 4;

    const float* simb  = simp + (size_t)g * KK * 256;
    const float* simb2 = simb + SIMSZ;
    const float* xb    = x + (size_t)n * C * PIX;
    float* ub = u + (size_t)n * C * PIX;

    int sqw[5], sqc[5], sqr[5];
#pragma unroll
    for (int i = 0; i < 5; i++) {
        int q  = tid + i * 512;
        sqw[i] = q & 15; sqc[i] = (q >> 4) & 15; sqr[i] = q >> 8;
    }

    float4 xs[5];
    {
        int c0 = cqb * 32;
#pragma unroll
        for (int i = 0; i < 5; i++) {
            int hh = h0 - 3 + sqr[i];
            float4 v = make_float4(0.f, 0.f, 0.f, 0.f);
            if ((unsigned)hh < 64u)
                v = *(const float4*)&xb[(size_t)(c0 + sqc[i]) * PIX + hh * 64 + sqw[i] * 4];
            xs[i] = v;
        }
    }

    {
        int ks = tid >> 8;
        int px = tid & 255;
        int k0 = ks ? 25 : 0;
        int nk = ks ? 24 : 25;
        float m = -1e30f;
        for (int i = 0; i < nk; i++) {
            size_t off = (size_t)(k0 + i) * 256 + px;
            m = fmaxf(m, simb[off] + simb2[off]);
        }
        mred[ks * 256 + px] = m;
        __syncthreads();
        m = fmaxf(mred[px], mred[256 + px]);
        float s = 0.f;
        for (int i = 0; i < nk; i++) {
            size_t off = (size_t)(k0 + i) * 256 + px;
            float e = __expf(simb[off] + simb2[off] - m);
            s += e;
            al[(k0 + i) * 256 + px] = (unsigned short)bf16rne(e);
        }
        sred[ks * 256 + px] = s;
        __syncthreads();
        if (ks == 0) sinv[px] = 1.f / (sred[px] + sred[256 + px]);
    }
    __syncthreads();

    for (int idx = tid; idx < 16 * 10 * 12; idx += 512) {
        int i12  = idx % 12;
        int rowc = idx / 12;
        int col  = (i12 < 4) ? i12 : 64 + i12;
        stb[rowc * SBW + col] = 0;
    }

#pragma unroll
    for (int i = 0; i < 5; i++) {
        uint2 p;
        p.x = packbf(xs[i].x, xs[i].y);
        p.y = packbf(xs[i].z, xs[i].w);
        *(uint2*)&stb[(sqc[i] * 10 + sqr[i]) * SBW + 4 + sqw[i] * 4] = p;
    }
    {
        int c1 = cqb * 32 + 16;
#pragma unroll
        for (int i = 0; i < 5; i++) {
            int hh = h0 - 3 + sqr[i];
            float4 v = make_float4(0.f, 0.f, 0.f, 0.f);
            if ((unsigned)hh < 64u)
                v = *(const float4*)&xb[(size_t)(c1 + sqc[i]) * PIX + hh * 64 + sqw[i] * 4];
            xs[i] = v;
        }
    }
    __syncthreads();

    int cw = wid * 2;
#pragma unroll
    for (int ch2 = 0; ch2 < 2; ch2++) {
        int c0 = cqb * 32 + ch2 * 16;
        float u4[2][4];
#pragma unroll
        for (int cl = 0; cl < 2; cl++)
#pragma unroll
            for (int j = 0; j < 4; j++) u4[cl][j] = 0.f;

        for (int di = 0; di < 7; di++) {
#pragma unroll
            for (int cl = 0; cl < 2; cl++) {
                const unsigned short* rp = &stb[((cw + cl) * 10 + r + di) * SBW + wpx];
                uint2 q0 = *(const uint2*)&rp[0];
                uint2 q1 = *(const uint2*)&rp[4];
                uint2 q2 = *(const uint2*)&rp[8];
                float rw[12];
                rw[0]  = bflo(q0.x); rw[1]  = bfhi(q0.x);
                rw[2]  = bflo(q0.y); rw[3]  = bfhi(q0.y);
                rw[4]  = bflo(q1.x); rw[5]  = bfhi(q1.x);
                rw[6]  = bflo(q1.y); rw[7]  = bfhi(q1.y);
                rw[8]  = bflo(q2.x); rw[9]  = bfhi(q2.x);
                rw[10] = bflo(q2.y); rw[11] = bfhi(q2.y);
#pragma unroll
                for (int dj = 0; dj < 7; dj++) {
                    uint2 p = *(const uint2*)&al[(di * 7 + dj) * 256 + r * 64 + wpx];
                    float a0 = bflo(p.x), a1 = bfhi(p.x);
                    float a2 = bflo(p.y), a3 = bfhi(p.y);
                    u4[cl][0] = fmaf(a0, rw[dj + 1], u4[cl][0]);
                    u4[cl][1] = fmaf(a1, rw[dj + 2], u4[cl][1]);
                    u4[cl][2] = fmaf(a2, rw[dj + 3], u4[cl][2]);
                    u4[cl][3] = fmaf(a3, rw[dj + 4], u4[cl][3]);
                }
            }
        }

        float4 s4 = *(const float4*)&sinv[r * 64 + wpx];
        const float* sp = (const float*)&s4;
#pragma unroll
        for (int cl = 0; cl < 2; cl++) {
            int c = c0 + cw + cl;
            float4 v = make_float4(u4[cl][0] * sp[0], u4[cl][1] * sp[1],
                                   u4[cl][2] * sp[2], u4[cl][3] * sp[3]);
            *(float4*)&ub[(size_t)c * PIX + (h0 + r) * 64 + wpx] = v;
        }

        if (ch2 == 0) {
            __syncthreads();
#pragma unroll
            for (int i = 0; i < 5; i++) {
                uint2 p;
                p.x = packbf(xs[i].x, xs[i].y);
                p.y = packbf(xs[i].z, xs[i].w);
                *(uint2*)&stb[(sqc[i] * 10 + sqr[i]) * SBW + 4 + sqw[i] * 4] = p;
            }
            __syncthreads();
        }
    }
}

// ---------------------------------------------------------------------------
extern "C" void kernel_launch(void* const* d_in, const int* in_sizes, int n_in,
                              void* d_out, int out_size, void* d_ws, size_t ws_size,
                              hipStream_t stream) {
    const float* x  = (const float*)d_in[0];
    const float* w1 = (const float*)d_in[1];
    const float* w2 = (const float*)d_in[2];
    const float* w3 = (const float*)d_in[3];
    float* wsf = (float*)d_ws;
    unsigned short* A1hi = (unsigned short*)wsf;
    unsigned short* A1lo = A1hi + 16384;
    unsigned short* A2hi = A1hi + 32768;
    unsigned short* A2lo = A1hi + 49152;

    prep<<<68, 256, 0, stream>>>(w1, w2, w3, A1hi, A1lo, A2hi, A2lo);
    convm<<<512, 256, 0, stream>>>(A1hi, A1lo, x, wsf + Z_OFF);             // z
    simk8<<<1792, 256, 0, stream>>>(wsf + Z_OFF, x, wsf + SIM_OFF);         // partial sims
    softpv9<<<512, 512, 0, stream>>>(wsf + SIM_OFF, x, wsf + U_OFF);        // fold+softmax+PV
    convm<<<512, 256, 0, stream>>>(A2hi, A2lo, wsf + U_OFF, (float*)d_out); // out
}